// Round 6
// baseline (134.125 us; speedup 1.0000x reference)
//
#include <hip/hip_runtime.h>
#include <stdint.h>

// Bert4Argument R13: out = seq·W1 (gathered K=768 GEMM)
//                        + pe_logits[l-pos+256]        (precomputed 528x208)
//                        + ce_logits[l==pos?frame:0]   (precomputed 208x208, bias folded)
// R12 post-mortem: K=64 dbuf + partial-wave A-staging + XCD swizzle = -5us vs R10.
// R13 = exact R10 structure (2-barrier K=128 x 6 chunks) with ONE change:
//   A never goes through LDS. Each compute lane gathers its own A fragment
//   (row p*16+n16 via head[], k = c*128+ks*32+quad*8) -> pack8 -> MFMA operand.
//   Removes 1 ds_write + 4 ds_read per thread/chunk; LDS 60->52 KB.
//   4x duplicate A loads (4 waves per p) are L1-served (8 KB/chunk working set).

typedef __attribute__((ext_vector_type(8))) short short8;
typedef __attribute__((ext_vector_type(4))) float f32x4;

#define AS1 __attribute__((address_space(1)))
#define AS3 __attribute__((address_space(3)))

// ---- workspace layout ----
// Wp bf16, 13 tiles x [kb8 0..95][n16][8] = 159744 shorts (319488 B)
// pe_logits f32 [528][208] at float off 79872
// ce_logits f32 [208][208] at float off 189696 (bias folded)
#define TILE_STRIDE 12288     // shorts per n-tile (96*16*8)
#define NT         13
#define NPE_RT     33         // 33*16 = 528 rows cover 513
#define NCE_RT     13         // 13*16 = 208 rows cover 201
#define NLOG      ((NPE_RT + NCE_RT) * NT)   // 598 logits tiles
#define NPACK      19968      // pack thread-units
#define PEL_OFF_F  79872
#define CEL_OFF_F  189696
#define WS_NEED_B  931840

__device__ __forceinline__ unsigned short f2bf(float f) {
    union { float f; unsigned int u; } v; v.f = f;
    unsigned int u = v.u;
    return (unsigned short)((u + 0x7fffu + ((u >> 16) & 1u)) >> 16);
}

__device__ __forceinline__ short8 pack8(f32x4 a, f32x4 b) {
    short8 r;
    r[0] = (short)f2bf(a.x); r[1] = (short)f2bf(a.y);
    r[2] = (short)f2bf(a.z); r[3] = (short)f2bf(a.w);
    r[4] = (short)f2bf(b.x); r[5] = (short)f2bf(b.y);
    r[6] = (short)f2bf(b.z); r[7] = (short)f2bf(b.w);
    return r;
}

__device__ __forceinline__ void dma16(const unsigned short* g, AS3 unsigned short* l) {
    __builtin_amdgcn_global_load_lds((AS1 const unsigned int*)g,
                                     (AS3 unsigned int*)l, 16, 0, 0);
}

// ---------------------------------------------------------------------------
// prep (identical to R10): blocks [0,598): logits tiles; [598,637): W pack.
// ---------------------------------------------------------------------------
__global__ __launch_bounds__(512) void prep_kernel(
    const float* __restrict__ pe,
    const float* __restrict__ ce,
    const float* __restrict__ W,
    const float* __restrict__ bias,
    unsigned short* __restrict__ ws)
{
    __shared__ float red[2048];

    if (blockIdx.x >= NLOG) {
        // ---- W pack: g = ((t*96 + kb8)*16 + n), k-range [0,768) ----
        const int g   = (blockIdx.x - NLOG) * 512 + threadIdx.x;   // < 19968 exact
        const int n   = g & 15;
        const int kb8 = (g >> 4) % 96;
        const int t   = g / 1536;
        const int row = t * 16 + n;
        const int col = kb8 * 8;
        f32x4 a = {0.f, 0.f, 0.f, 0.f}, b = {0.f, 0.f, 0.f, 0.f};
        if (row < 200) {
            const float* p = W + (size_t)row * 2304 + col;
            a = *(const f32x4*)p;
            b = *(const f32x4*)(p + 4);
        }
        *(short8*)(ws + (size_t)g * 8) = pack8(a, b);
        return;
    }

    // ---- logits ----
    const int bb   = blockIdx.x;
    const int w    = threadIdx.x >> 6;
    const int lane = threadIdx.x & 63;
    const int n16  = lane & 15;
    const int quad = lane >> 4;

    float* wsF = (float*)ws;
    int rowtile, t, nrows, koff;
    const float* A;
    float* outL;
    bool isCe;
    if (bb < NPE_RT * NT) {
        isCe = false; rowtile = bb / NT; t = bb % NT;
        nrows = 513; koff = 768;  A = pe; outL = wsF + PEL_OFF_F;
    } else {
        const int b2 = bb - NPE_RT * NT;
        isCe = true;  rowtile = b2 / NT; t = b2 % NT;
        nrows = 201; koff = 1536; A = ce; outL = wsF + CEL_OFF_F;
    }

    int arow = rowtile * 16 + n16;
    if (arow >= nrows) arow = nrows - 1;            // clamped rows never written
    const float* abase = A + (size_t)arow * 768 + w * 96 + quad * 8;

    const int col  = t * 16 + n16;                  // cols >= 200 junk, never read
    const int wrow = (col < 200) ? col : 0;
    const float* wbase = W + (size_t)wrow * 2304 + koff + w * 96 + quad * 8;

    // all 12 loads issued before any use: one latency round-trip
    f32x4 av0[3], av1[3], wv0[3], wv1[3];
#pragma unroll
    for (int ks = 0; ks < 3; ++ks) {
        av0[ks] = *(const f32x4*)(abase + ks * 32);
        av1[ks] = *(const f32x4*)(abase + ks * 32 + 4);
        wv0[ks] = *(const f32x4*)(wbase + ks * 32);
        wv1[ks] = *(const f32x4*)(wbase + ks * 32 + 4);
    }
    f32x4 acc = (f32x4){0.f, 0.f, 0.f, 0.f};
#pragma unroll
    for (int ks = 0; ks < 3; ++ks)
        acc = __builtin_amdgcn_mfma_f32_16x16x32_bf16(
            pack8(av0[ks], av1[ks]), pack8(wv0[ks], wv1[ks]), acc, 0, 0, 0);

#pragma unroll
    for (int r = 0; r < 4; ++r)
        red[w * 256 + lane * 4 + r] = acc[r];
    __syncthreads();
    if (threadIdx.x < 64) {
        const float bv = (isCe && col < 200) ? bias[col] : 0.0f;
#pragma unroll
        for (int r = 0; r < 4; ++r) {
            float s = 0.f;
#pragma unroll
            for (int ww = 0; ww < 8; ++ww)
                s += red[ww * 256 + lane * 4 + r];
            const int row = rowtile * 16 + quad * 4 + r;
            if (row < nrows)
                outL[(size_t)row * 208 + col] = s + bv;
        }
    }
}

// ---------------------------------------------------------------------------
// Main GEMM: seq-part only, K=768 (6 chunks of 128). grid 512 x 512 thr.
// Block = 32 rows x all 13 n-tiles. LDS = B ONLY: 13 tiles x 2048 shorts (52 KB),
// tile t at t*2048 + (ks*4+quad)*128 + n16*8.
// A: per-lane direct gather to registers (no LDS): lane l of wave (p=w&1) holds
//    row p*16+(l&15) via head[], k = cc*128 + ks*32 + (l>>4)*8; f32x4 x2 -> pack8.
//    Next chunk's 8 loads issued right after barrier (fly under MFMA).
// B: dma16 from Wp, 52 units/chunk over 8 waves. 2 barriers/chunk (R10 schedule).
// Epilogue: + pe_logits[rel,col] + ce_logits[cls,col] (bias inside), write f32.
// ---------------------------------------------------------------------------
__global__ __launch_bounds__(512, 4) void gemm_kernel(
    const unsigned short* __restrict__ ws,
    const float* __restrict__ seq,
    const int*   __restrict__ head,
    const int*   __restrict__ frame,
    const int*   __restrict__ pos,
    float* __restrict__ out)
{
    __shared__ unsigned short lds[13 * 2048];   // 53248 B

    const unsigned short* Wp = ws;
    const float* wsF = (const float*)ws;
    const float* peL = wsF + PEL_OFF_F;
    const float* ceL = wsF + CEL_OFF_F;

    const int tid  = threadIdx.x;
    const int wave = tid >> 6;
    const int lane = tid & 63;
    const int n16  = lane & 15;
    const int quad = lane >> 4;

    const int mblk    = blockIdx.x;          // 32 rows
    const int i       = mblk >> 3;
    const int pos_i   = pos[i];
    const int frame_i = frame[i];

    // ---- compute partition: p = m-frag, q -> tiles q+4u ----
    const int p = wave & 1;
    const int q = wave >> 1;

    // ---- per-lane A gather base: row p*16+n16, k-sub quad*8 ----
    const int srow = mblk * 32 + p * 16 + n16;
    const int hi   = head[srow];
    const float* aP = seq + ((size_t)i * 256 + hi) * 768 + quad * 8;

    const unsigned short* bRd[4];
    bool uok[4];
#pragma unroll
    for (int u = 0; u < 4; ++u) {
        const int t = q + 4 * u;
        uok[u] = (t < NT);
        bRd[u] = lds + (uok[u] ? t : 0) * 2048 + quad * 128 + n16 * 8;
    }

    f32x4 acc[4];
#pragma unroll
    for (int u = 0; u < 4; ++u)
        acc[u] = (f32x4){0.f, 0.f, 0.f, 0.f};

    // prologue: issue A loads for chunk 0 (8 x f32x4 in flight)
    f32x4 av0[4], av1[4];
#pragma unroll
    for (int ks = 0; ks < 4; ++ks) {
        av0[ks] = *(const f32x4*)(aP + ks * 32);
        av1[ks] = *(const f32x4*)(aP + ks * 32 + 4);
    }

    for (int cc = 0; cc < 6; ++cc) {
        // ---- issue B dma for this chunk (52 units over 8 waves) ----
#pragma unroll
        for (int un = wave; un < 52; un += 8) {
            const int t = un >> 2, part = un & 3;
            dma16(Wp + (size_t)t * TILE_STRIDE + cc * 2048 + part * 512 + lane * 8,
                  (AS3 unsigned short*)lds + t * 2048 + part * 512 + lane * 8);
        }
        // ---- pack current A while dma flies (VALU only) ----
        short8 pa[4];
#pragma unroll
        for (int ks = 0; ks < 4; ++ks)
            pa[ks] = pack8(av0[ks], av1[ks]);
        __syncthreads();                       // B(cc) resident
        // ---- issue next chunk's A loads: fly under MFMA ----
        if (cc < 5) {
            const float* ap = aP + (cc + 1) * 128;
#pragma unroll
            for (int ks = 0; ks < 4; ++ks) {
                av0[ks] = *(const f32x4*)(ap + ks * 32);
                av1[ks] = *(const f32x4*)(ap + ks * 32 + 4);
            }
        }
        // ---- compute: 4 ks x 4 u MFMA ----
#pragma unroll
        for (int ks = 0; ks < 4; ++ks) {
#pragma unroll
            for (int u = 0; u < 4; ++u) {
                if (uok[u]) {
                    short8 bf = *(const short8*)(bRd[u] + ks * 512);
                    acc[u] = __builtin_amdgcn_mfma_f32_16x16x32_bf16(pa[ks], bf, acc[u], 0, 0, 0);
                }
            }
        }
        __syncthreads();                       // protect B LDS overwrite
    }

    // epilogue: C/D col = lane&15, row = quad*4 + r; add gathered logits
    const int rbase = mblk * 32 + p * 16 + quad * 4;
#pragma unroll
    for (int u = 0; u < 4; ++u) {
        if (uok[u]) {
            const int col = (q + 4 * u) * 16 + n16;
            if (col < 200) {
#pragma unroll
                for (int r = 0; r < 4; ++r) {
                    const int row = rbase + r;
                    const int l   = row & 255;
                    const int rel = l - pos_i + 256;
                    const int cls = (l == pos_i) ? frame_i : 0;
                    out[(size_t)row * 200 + col] =
                        acc[u][r] + peL[(size_t)rel * 208 + col]
                                  + ceL[(size_t)cls * 208 + col];
                }
            }
        }
    }
}

// ---------------------------------------------------------------------------
// Fallback (no workspace): slow but correct, f32 W converted inline.
// ---------------------------------------------------------------------------
__global__ __launch_bounds__(256) void gemm_fallback(
    const float* __restrict__ seq, const float* __restrict__ pe,
    const float* __restrict__ ce, const float* __restrict__ Wf,
    const float* __restrict__ bias, const int* __restrict__ head,
    const int* __restrict__ frame, const int* __restrict__ pos,
    float* __restrict__ out)
{
    const int tid  = threadIdx.x;
    const int wave = tid >> 6;
    const int lane = tid & 63;
    const int n16  = lane & 15;
    const int quad = lane >> 4;

    const int mrow  = blockIdx.x * 16 + n16;
    const int i     = mrow >> 8;
    const int j     = mrow & 255;
    const int pos_i = pos[i];
    const int hi    = head[mrow];
    const int rel   = j - pos_i + 256;
    const int cls   = (j == pos_i) ? frame[i] : 0;

    const float* segs[3];
    segs[0] = seq + ((size_t)i * 256 + (size_t)hi) * 768 + quad * 8;
    segs[1] = pe + (size_t)rel * 768 + quad * 8;
    segs[2] = ce + (size_t)cls * 768 + quad * 8;

    const int ntl = (wave == 0) ? 4 : 3;
    f32x4 acc[4];
#pragma unroll
    for (int u = 0; u < 4; ++u) {
        const int t = wave + 4 * u;
        const int col = t * 16 + n16;
        const float bv = (t < 13 && col < 200) ? bias[col] : 0.0f;
        acc[u] = (f32x4){bv, bv, bv, bv};
    }

    for (int s = 0; s < 3; ++s) {
        const float* ap = segs[s];
#pragma unroll 2
        for (int kk = 0; kk < 768; kk += 32) {
            short8 afr = pack8(*(const f32x4*)(ap + kk), *(const f32x4*)(ap + kk + 4));
#pragma unroll
            for (int u = 0; u < 4; ++u) {
                if (u < ntl) {
                    const int t = wave + 4 * u;
                    const int row = t * 16 + n16;
                    short8 bfr = {0, 0, 0, 0, 0, 0, 0, 0};
                    if (row < 200) {
                        const float* qp = Wf + (size_t)row * 2304 + s * 768 + kk + quad * 8;
                        bfr = pack8(*(const f32x4*)qp, *(const f32x4*)(qp + 4));
                    }
                    acc[u] = __builtin_amdgcn_mfma_f32_16x16x32_bf16(afr, bfr, acc[u], 0, 0, 0);
                }
            }
        }
    }

    const int rbase = blockIdx.x * 16 + quad * 4;
#pragma unroll
    for (int u = 0; u < 4; ++u) {
        const int t = wave + 4 * u;
        if (t < 13) {
            const int col = t * 16 + n16;
            if (col < 200) {
#pragma unroll
                for (int r = 0; r < 4; ++r)
                    out[(size_t)(rbase + r) * 200 + col] = acc[u][r];
            }
        }
    }
}

// ---------------------------------------------------------------------------
extern "C" void kernel_launch(void* const* d_in, const int* in_sizes, int n_in,
                              void* d_out, int out_size, void* d_ws, size_t ws_size,
                              hipStream_t stream) {
    const float* seq  = (const float*)d_in[0];
    const float* pe   = (const float*)d_in[1];
    const float* ce   = (const float*)d_in[2];
    const float* W    = (const float*)d_in[3];
    const float* bias = (const float*)d_in[4];
    const int* head   = (const int*)d_in[5];
    const int* frame  = (const int*)d_in[6];
    const int* pos    = (const int*)d_in[7];
    float* out = (float*)d_out;

    if (d_ws != nullptr && ws_size >= (size_t)WS_NEED_B) {
        unsigned short* ws = (unsigned short*)d_ws;
        prep_kernel<<<NLOG + (NPACK + 511) / 512, 512, 0, stream>>>(
            pe, ce, W, bias, ws);
        gemm_kernel<<<512, 512, 0, stream>>>(ws, seq, head, frame, pos, out);
    } else {
        gemm_fallback<<<1024, 256, 0, stream>>>(seq, pe, ce, W, bias, head,
                                                frame, pos, out);
    }
}

// Round 7
// 119.499 us; speedup vs baseline: 1.1224x; 1.1224x over previous
//
#include <hip/hip_runtime.h>
#include <stdint.h>

// Bert4Argument R14 = exact R10 revert (session best, 120.0 us).
// out = seq·W1 (gathered K=768 GEMM)
//     + pe_logits[l-pos+256]        (precomputed 528x208)
//     + ce_logits[l==pos?frame:0]   (precomputed 208x208, bias folded)
// Session ledger: R10=120.0 | R12 (K64 dbuf + XCD swz) = 125.0 REJECTED
//               | R13 (A direct-gather, no LDS) = 134.1 REJECTED
// R10's gemm sits ~2us above its 10us HBM floor (seq 46-50MB + out 13MB @6.3TB/s);
// the 2x 256MiB workspace-poison fills (~83us) are fixed harness cost.

typedef __attribute__((ext_vector_type(8))) short short8;
typedef __attribute__((ext_vector_type(4))) float f32x4;

#define AS1 __attribute__((address_space(1)))
#define AS3 __attribute__((address_space(3)))

// ---- workspace layout ----
// Wp bf16, 13 tiles x [kb8 0..95][n16][8] = 159744 shorts (319488 B)
// pe_logits f32 [528][208] at float off 79872
// ce_logits f32 [208][208] at float off 189696 (bias folded)
#define TILE_STRIDE 12288     // shorts per n-tile (96*16*8)
#define NT         13
#define NPE_RT     33         // 33*16 = 528 rows cover 513
#define NCE_RT     13         // 13*16 = 208 rows cover 201
#define NLOG      ((NPE_RT + NCE_RT) * NT)   // 598 logits tiles
#define NPACK      19968      // pack thread-units
#define PEL_OFF_F  79872
#define CEL_OFF_F  189696
#define WS_NEED_B  931840

__device__ __forceinline__ unsigned short f2bf(float f) {
    union { float f; unsigned int u; } v; v.f = f;
    unsigned int u = v.u;
    return (unsigned short)((u + 0x7fffu + ((u >> 16) & 1u)) >> 16);
}

__device__ __forceinline__ short8 pack8(f32x4 a, f32x4 b) {
    short8 r;
    r[0] = (short)f2bf(a.x); r[1] = (short)f2bf(a.y);
    r[2] = (short)f2bf(a.z); r[3] = (short)f2bf(a.w);
    r[4] = (short)f2bf(b.x); r[5] = (short)f2bf(b.y);
    r[6] = (short)f2bf(b.z); r[7] = (short)f2bf(b.w);
    return r;
}

__device__ __forceinline__ void dma16(const unsigned short* g, AS3 unsigned short* l) {
    __builtin_amdgcn_global_load_lds((AS1 const unsigned int*)g,
                                     (AS3 unsigned int*)l, 16, 0, 0);
}

// ---------------------------------------------------------------------------
// prep: blocks [0,598): logits. Block = one 16x16 output tile (rowtile x ntile).
//       8 waves K-split 96 each (3 steps of 32), LDS reduce, wave 0 writes.
//       blocks [598,637): pack W[:,0:768] f32 -> bf16 13-tile layout (rows>=200 zero).
// ---------------------------------------------------------------------------
__global__ __launch_bounds__(512) void prep_kernel(
    const float* __restrict__ pe,
    const float* __restrict__ ce,
    const float* __restrict__ W,
    const float* __restrict__ bias,
    unsigned short* __restrict__ ws)
{
    __shared__ float red[2048];

    if (blockIdx.x >= NLOG) {
        // ---- W pack: g = ((t*96 + kb8)*16 + n), k-range [0,768) ----
        const int g   = (blockIdx.x - NLOG) * 512 + threadIdx.x;   // < 19968 exact
        const int n   = g & 15;
        const int kb8 = (g >> 4) % 96;
        const int t   = g / 1536;
        const int row = t * 16 + n;
        const int col = kb8 * 8;
        f32x4 a = {0.f, 0.f, 0.f, 0.f}, b = {0.f, 0.f, 0.f, 0.f};
        if (row < 200) {
            const float* p = W + (size_t)row * 2304 + col;
            a = *(const f32x4*)p;
            b = *(const f32x4*)(p + 4);
        }
        *(short8*)(ws + (size_t)g * 8) = pack8(a, b);
        return;
    }

    // ---- logits ----
    const int bb   = blockIdx.x;
    const int w    = threadIdx.x >> 6;
    const int lane = threadIdx.x & 63;
    const int n16  = lane & 15;
    const int quad = lane >> 4;

    float* wsF = (float*)ws;
    int rowtile, t, nrows, koff;
    const float* A;
    float* outL;
    bool isCe;
    if (bb < NPE_RT * NT) {
        isCe = false; rowtile = bb / NT; t = bb % NT;
        nrows = 513; koff = 768;  A = pe; outL = wsF + PEL_OFF_F;
    } else {
        const int b2 = bb - NPE_RT * NT;
        isCe = true;  rowtile = b2 / NT; t = b2 % NT;
        nrows = 201; koff = 1536; A = ce; outL = wsF + CEL_OFF_F;
    }

    int arow = rowtile * 16 + n16;
    if (arow >= nrows) arow = nrows - 1;            // clamped rows never written
    const float* abase = A + (size_t)arow * 768 + w * 96 + quad * 8;

    const int col  = t * 16 + n16;                  // cols >= 200 junk, never read
    const int wrow = (col < 200) ? col : 0;
    const float* wbase = W + (size_t)wrow * 2304 + koff + w * 96 + quad * 8;

    // all 12 loads issued before any use: one latency round-trip
    f32x4 av0[3], av1[3], wv0[3], wv1[3];
#pragma unroll
    for (int ks = 0; ks < 3; ++ks) {
        av0[ks] = *(const f32x4*)(abase + ks * 32);
        av1[ks] = *(const f32x4*)(abase + ks * 32 + 4);
        wv0[ks] = *(const f32x4*)(wbase + ks * 32);
        wv1[ks] = *(const f32x4*)(wbase + ks * 32 + 4);
    }
    f32x4 acc = (f32x4){0.f, 0.f, 0.f, 0.f};
#pragma unroll
    for (int ks = 0; ks < 3; ++ks)
        acc = __builtin_amdgcn_mfma_f32_16x16x32_bf16(
            pack8(av0[ks], av1[ks]), pack8(wv0[ks], wv1[ks]), acc, 0, 0, 0);

#pragma unroll
    for (int r = 0; r < 4; ++r)
        red[w * 256 + lane * 4 + r] = acc[r];
    __syncthreads();
    if (threadIdx.x < 64) {
        const float bv = (isCe && col < 200) ? bias[col] : 0.0f;
#pragma unroll
        for (int r = 0; r < 4; ++r) {
            float s = 0.f;
#pragma unroll
            for (int ww = 0; ww < 8; ++ww)
                s += red[ww * 256 + lane * 4 + r];
            const int row = rowtile * 16 + quad * 4 + r;
            if (row < nrows)
                outL[(size_t)row * 208 + col] = s + bv;
        }
    }
}

// ---------------------------------------------------------------------------
// Main GEMM: seq-part only, K=768 (6 chunks of 128). grid 512 x 512 thr.
// Block = 32 rows (mblk) x ALL 13 n-tiles -> A read once from HBM (50 MB).
// LDS 60 KB: A 8 slabs (fm 0..1, ks 0..3) of 64x8 bf16 at ((fm*4+ks)*64+lane)*8;
//            B 13 tiles x 2048 shorts at 4096 + t*2048 + (ks*4+quad)*128 + n16*8.
// A: gathered f32 loads issued one chunk EARLY, cvt->ds_write (1 slab/wave).
// B: dma16 from Wp, 52 units/chunk over 8 waves.
// Compute: wave w -> m-frag p=w&1, tiles q+4u (q=w>>1, u<4, t<13).
// Epilogue: + pe_logits[rel,col] + ce_logits[cls,col] (bias inside), write f32.
// ---------------------------------------------------------------------------
__global__ __launch_bounds__(512, 4) void gemm_kernel(
    const unsigned short* __restrict__ ws,
    const float* __restrict__ seq,
    const int*   __restrict__ head,
    const int*   __restrict__ frame,
    const int*   __restrict__ pos,
    float* __restrict__ out)
{
    __shared__ unsigned short lds[4096 + 13 * 2048];   // 61440 B

    const unsigned short* Wp = ws;
    const float* wsF = (const float*)ws;
    const float* peL = wsF + PEL_OFF_F;
    const float* ceL = wsF + CEL_OFF_F;

    const int tid  = threadIdx.x;
    const int wave = tid >> 6;
    const int lane = tid & 63;
    const int n16  = lane & 15;
    const int quad = lane >> 4;

    const int mblk    = blockIdx.x;          // 32 rows
    const int i       = mblk >> 3;
    const int pos_i   = pos[i];
    const int frame_i = frame[i];

    // ---- A staging: wave stages slab (sfm = wave&1, sk = wave>>1) ----
    const int sfm = wave & 1;
    const int sk  = wave >> 1;               // 0..3
    const int srow = mblk * 32 + sfm * 16 + n16;
    const int hi   = head[srow];
    const float* aP = seq + ((size_t)i * 256 + hi) * 768 + sk * 32 + quad * 8;
    unsigned short* aDst = (unsigned short*)lds + ((sfm * 4 + sk) * 64 + lane) * 8;

    // ---- compute partition: p = m-frag, q -> tiles q+4u ----
    const int p = wave & 1;
    const int q = wave >> 1;
    const unsigned short* aRd = lds + p * 2048 + lane * 8;
    const unsigned short* bRd[4];
    bool uok[4];
#pragma unroll
    for (int u = 0; u < 4; ++u) {
        const int t = q + 4 * u;
        uok[u] = (t < NT);
        bRd[u] = lds + 4096 + (uok[u] ? t : 0) * 2048 + quad * 128 + n16 * 8;
    }

    f32x4 acc[4];
#pragma unroll
    for (int u = 0; u < 4; ++u)
        acc[u] = (f32x4){0.f, 0.f, 0.f, 0.f};

    // prologue: issue A loads for chunk 0
    f32x4 a0 = *(const f32x4*)(aP);
    f32x4 a1 = *(const f32x4*)(aP + 4);

    for (int cc = 0; cc < 6; ++cc) {
        // stage A (regs -> LDS) and B (dma16: 52 units over 8 waves)
        *(short8*)aDst = pack8(a0, a1);
#pragma unroll
        for (int un = wave; un < 52; un += 8) {
            const int t = un >> 2, part = un & 3;
            dma16(Wp + (size_t)t * TILE_STRIDE + cc * 2048 + part * 512 + lane * 8,
                  (AS3 unsigned short*)lds + 4096 + t * 2048 + part * 512 + lane * 8);
        }
        __syncthreads();
        // issue next chunk's A loads early: latency hides under MFMA below
        if (cc < 5) {
            const float* ap = aP + (cc + 1) * 128;
            a0 = *(const f32x4*)(ap);
            a1 = *(const f32x4*)(ap + 4);
        }
#pragma unroll
        for (int ks = 0; ks < 4; ++ks) {
            short8 af = *(const short8*)(aRd + ks * 512);
#pragma unroll
            for (int u = 0; u < 4; ++u) {
                if (uok[u]) {
                    short8 bf = *(const short8*)(bRd[u] + ks * 512);
                    acc[u] = __builtin_amdgcn_mfma_f32_16x16x32_bf16(af, bf, acc[u], 0, 0, 0);
                }
            }
        }
        __syncthreads();
    }

    // epilogue: C/D col = lane&15, row = quad*4 + r; add gathered logits
    const int rbase = mblk * 32 + p * 16 + quad * 4;
#pragma unroll
    for (int u = 0; u < 4; ++u) {
        if (uok[u]) {
            const int col = (q + 4 * u) * 16 + n16;
            if (col < 200) {
#pragma unroll
                for (int r = 0; r < 4; ++r) {
                    const int row = rbase + r;
                    const int l   = row & 255;
                    const int rel = l - pos_i + 256;
                    const int cls = (l == pos_i) ? frame_i : 0;
                    out[(size_t)row * 200 + col] =
                        acc[u][r] + peL[(size_t)rel * 208 + col]
                                  + ceL[(size_t)cls * 208 + col];
                }
            }
        }
    }
}

// ---------------------------------------------------------------------------
// Fallback (no workspace): slow but correct, f32 W converted inline.
// ---------------------------------------------------------------------------
__global__ __launch_bounds__(256) void gemm_fallback(
    const float* __restrict__ seq, const float* __restrict__ pe,
    const float* __restrict__ ce, const float* __restrict__ Wf,
    const float* __restrict__ bias, const int* __restrict__ head,
    const int* __restrict__ frame, const int* __restrict__ pos,
    float* __restrict__ out)
{
    const int tid  = threadIdx.x;
    const int wave = tid >> 6;
    const int lane = tid & 63;
    const int n16  = lane & 15;
    const int quad = lane >> 4;

    const int mrow  = blockIdx.x * 16 + n16;
    const int i     = mrow >> 8;
    const int j     = mrow & 255;
    const int pos_i = pos[i];
    const int hi    = head[mrow];
    const int rel   = j - pos_i + 256;
    const int cls   = (j == pos_i) ? frame[i] : 0;

    const float* segs[3];
    segs[0] = seq + ((size_t)i * 256 + (size_t)hi) * 768 + quad * 8;
    segs[1] = pe + (size_t)rel * 768 + quad * 8;
    segs[2] = ce + (size_t)cls * 768 + quad * 8;

    const int ntl = (wave == 0) ? 4 : 3;
    f32x4 acc[4];
#pragma unroll
    for (int u = 0; u < 4; ++u) {
        const int t = wave + 4 * u;
        const int col = t * 16 + n16;
        const float bv = (t < 13 && col < 200) ? bias[col] : 0.0f;
        acc[u] = (f32x4){bv, bv, bv, bv};
    }

    for (int s = 0; s < 3; ++s) {
        const float* ap = segs[s];
#pragma unroll 2
        for (int kk = 0; kk < 768; kk += 32) {
            short8 afr = pack8(*(const f32x4*)(ap + kk), *(const f32x4*)(ap + kk + 4));
#pragma unroll
            for (int u = 0; u < 4; ++u) {
                if (u < ntl) {
                    const int t = wave + 4 * u;
                    const int row = t * 16 + n16;
                    short8 bfr = {0, 0, 0, 0, 0, 0, 0, 0};
                    if (row < 200) {
                        const float* qp = Wf + (size_t)row * 2304 + s * 768 + kk + quad * 8;
                        bfr = pack8(*(const f32x4*)qp, *(const f32x4*)(qp + 4));
                    }
                    acc[u] = __builtin_amdgcn_mfma_f32_16x16x32_bf16(afr, bfr, acc[u], 0, 0, 0);
                }
            }
        }
    }

    const int rbase = blockIdx.x * 16 + quad * 4;
#pragma unroll
    for (int u = 0; u < 4; ++u) {
        const int t = wave + 4 * u;
        if (t < 13) {
            const int col = t * 16 + n16;
            if (col < 200) {
#pragma unroll
                for (int r = 0; r < 4; ++r)
                    out[(size_t)(rbase + r) * 200 + col] = acc[u][r];
            }
        }
    }
}

// ---------------------------------------------------------------------------
extern "C" void kernel_launch(void* const* d_in, const int* in_sizes, int n_in,
                              void* d_out, int out_size, void* d_ws, size_t ws_size,
                              hipStream_t stream) {
    const float* seq  = (const float*)d_in[0];
    const float* pe   = (const float*)d_in[1];
    const float* ce   = (const float*)d_in[2];
    const float* W    = (const float*)d_in[3];
    const float* bias = (const float*)d_in[4];
    const int* head   = (const int*)d_in[5];
    const int* frame  = (const int*)d_in[6];
    const int* pos    = (const int*)d_in[7];
    float* out = (float*)d_out;

    if (d_ws != nullptr && ws_size >= (size_t)WS_NEED_B) {
        unsigned short* ws = (unsigned short*)d_ws;
        prep_kernel<<<NLOG + (NPACK + 511) / 512, 512, 0, stream>>>(
            pe, ce, W, bias, ws);
        gemm_kernel<<<512, 512, 0, stream>>>(ws, seq, head, frame, pos, out);
    } else {
        gemm_fallback<<<1024, 256, 0, stream>>>(seq, pe, ce, W, bias, head,
                                                frame, pos, out);
    }
}